// Round 13
// baseline (458.472 us; speedup 1.0000x reference)
//
#include <hip/hip_runtime.h>
#include <hip/hip_bf16.h>

#define N_NODES 8192
#define IN_F    256
#define OUT_F   64
#define ALPHA   0.3f
#define MBIAS   20.0f            // >= max dst_j; softmax exact after l-division
#define CSPL    8                // column splits
#define COLS_PER (N_NODES / CSPL)    // 1024
#define NTILES  (COLS_PER / 64)      // 16
#define MST     17               // Mlds row stride (u64): 16 + 1

typedef unsigned short u16;
typedef unsigned int   u32;
typedef unsigned long long u64;
typedef __attribute__((ext_vector_type(8))) short bf16x8;
typedef __attribute__((ext_vector_type(4))) float f32x4;

__device__ __forceinline__ float bf2f(u32 u) { return __uint_as_float(u << 16); }
__device__ __forceinline__ u32 f2bfbits(float x) {          // RNE f32->bf16
    u32 u = __float_as_uint(x);
    return (u + 0x7FFFu + ((u >> 16) & 1u)) >> 16;
}
__device__ __forceinline__ float lrelu(float s) { return s > 0.f ? s : ALPHA * s; }

// dtype probe: adj[0,0] == 1.0 always. bf16 -> low16 of first word = 0x3F80.
__device__ __forceinline__ int detect_bf16(const void* adj) {
    return ((((const u32*)adj)[0] & 0xFFFFu) == 0x3F80u) ? 1 : 0;
}

template <bool BF16>
__device__ __forceinline__ float ld(const void* p, size_t idx) {
    if constexpr (BF16) return bf2f(((const u16*)p)[idx]);
    else                return ((const float*)p)[idx];
}

// ---------------------------------------------------------------------------
// Kernel 1: Wh = h @ W. 4 rows per wave (W read once per 4 rows), 16 rows
// per block. Emits WhT [64][8192] bf16 scratch, src/dst fp32. (R9-proven)
// ---------------------------------------------------------------------------
template <bool BF16>
__device__ __forceinline__ void wh4_impl(
    const void* __restrict__ h, const void* __restrict__ W,
    const void* __restrict__ a, float* __restrict__ src,
    float* __restrict__ dst, int i0, int lane, float* accv)
{
    float acc0 = 0.f, acc1 = 0.f, acc2 = 0.f, acc3 = 0.f;
#pragma unroll 8
    for (int k = 0; k < IN_F; ++k) {
        float wv = ld<BF16>(W, (size_t)k * OUT_F + lane);      // coalesced
        float h0 = ld<BF16>(h, (size_t)(i0 + 0) * IN_F + k);   // wave-uniform
        float h1 = ld<BF16>(h, (size_t)(i0 + 1) * IN_F + k);
        float h2 = ld<BF16>(h, (size_t)(i0 + 2) * IN_F + k);
        float h3 = ld<BF16>(h, (size_t)(i0 + 3) * IN_F + k);
        acc0 = fmaf(h0, wv, acc0);
        acc1 = fmaf(h1, wv, acc1);
        acc2 = fmaf(h2, wv, acc2);
        acc3 = fmaf(h3, wv, acc3);
    }
    float av = ld<BF16>(a, lane);
    float bv = ld<BF16>(a, OUT_F + lane);
    float accs[4] = {acc0, acc1, acc2, acc3};
#pragma unroll
    for (int r = 0; r < 4; ++r) {
        float ps = accs[r] * av, pd = accs[r] * bv;
#pragma unroll
        for (int off = 32; off > 0; off >>= 1) {
            ps += __shfl_xor(ps, off, 64);
            pd += __shfl_xor(pd, off, 64);
        }
        if (lane == 0) { src[i0 + r] = ps; dst[i0 + r] = pd; }
        accv[r] = accs[r];
    }
}

__global__ __launch_bounds__(256) void gat_wh_kernel(
    const void* __restrict__ h, const void* __restrict__ W,
    const void* __restrict__ a, const void* __restrict__ adj,
    u16* __restrict__ WhT, float* __restrict__ src, float* __restrict__ dst)
{
    __shared__ float accs[16][OUT_F];
    const int tid = threadIdx.x, wave = tid >> 6, lane = tid & 63;
    const int i0 = blockIdx.x * 16 + wave * 4;
    float av[4];
    if (detect_bf16(adj)) wh4_impl<true >(h, W, a, src, dst, i0, lane, av);
    else                  wh4_impl<false>(h, W, a, src, dst, i0, lane, av);
#pragma unroll
    for (int r = 0; r < 4; ++r) accs[wave * 4 + r][lane] = av[r];
    __syncthreads();
    if (tid < OUT_F) {                    // WhT[f][i0..i0+15], bf16 scratch
        u32 w[8];
#pragma unroll
        for (int e = 0; e < 8; ++e) {
            u32 lo = f2bfbits(accs[2 * e][tid]);
            u32 hi = f2bfbits(accs[2 * e + 1][tid]);
            w[e] = lo | (hi << 16);
        }
        u16* dstp = WhT + (size_t)tid * N_NODES + blockIdx.x * 16;
        *(uint4*)dstp       = *(uint4*)&w[0];
        *(uint4*)(dstp + 8) = *(uint4*)&w[4];
    }
}

// ---------------------------------------------------------------------------
// Kernel 2: fused adj-stream + masked-softmax @ Wh via MFMA.
// Block = 64 rows x 1024 cols; grid 128x8 tiles adj disjointly.
// Prologue: adj->bitmask via lane-strided coalesced loads + __ballot
// (R12-proven idiom) into 8.5 KB LDS; dst window 4 KB LDS. ONE barrier.
// K-loop (16 tiles x 2 k-steps): barrier-free. P fragments built in-register
// (A-layout row=lane&15, k=(lane>>4)*8+j) from LDS mask+dst; B fragments
// loaded per-wave DIRECTLY from WhT global (16B/lane, L2-resident, 1-step
// prefetch). No B LDS, no staging barriers.
// ---------------------------------------------------------------------------
__global__ __launch_bounds__(256, 4) void gat_attn_kernel(
    const void* __restrict__ adj, const u16* __restrict__ WhT,
    const float* __restrict__ src, const float* __restrict__ dst,
    float* __restrict__ O_part, float* __restrict__ l_part)
{
    __shared__ alignas(16) u64  Mlds[64 * MST];     // 8704 B
    __shared__ alignas(16) float Dlds[COLS_PER];    // 4096 B

    const int tid = threadIdx.x, wave = tid >> 6, lane = tid & 63;
    const int i0 = blockIdx.x * 64, c0 = blockIdx.y * COLS_PER;
    const int isbf = detect_bf16(adj);

    // ---- stage dst window (coalesced) ----
#pragma unroll
    for (int q = 0; q < COLS_PER / 256; ++q)
        Dlds[q * 256 + tid] = dst[c0 + q * 256 + tid];

    // ---- stage adj bitmask: wave w handles rows 16w..16w+15 ----
    if (isbf) {
        const u16* base = (const u16*)adj;
        for (int rr = 0; rr < 16; ++rr) {
            const int row = wave * 16 + rr;
            const u16* p = base + (size_t)(i0 + row) * N_NODES + c0;
#pragma unroll
            for (int g = 0; g < 4; ++g) {
                u64 b0 = __ballot(p[(g * 4 + 0) * 64 + lane] != 0);
                u64 b1 = __ballot(p[(g * 4 + 1) * 64 + lane] != 0);
                u64 b2 = __ballot(p[(g * 4 + 2) * 64 + lane] != 0);
                u64 b3 = __ballot(p[(g * 4 + 3) * 64 + lane] != 0);
                u64 v = (lane == 0) ? b0 : (lane == 1) ? b1 : (lane == 2) ? b2 : b3;
                if (lane < 4) Mlds[row * MST + g * 4 + lane] = v;
            }
        }
    } else {
        const float* base = (const float*)adj;
        for (int rr = 0; rr < 16; ++rr) {
            const int row = wave * 16 + rr;
            const float* p = base + (size_t)(i0 + row) * N_NODES + c0;
#pragma unroll
            for (int g = 0; g < 4; ++g) {
                u64 b0 = __ballot(p[(g * 4 + 0) * 64 + lane] != 0.f);
                u64 b1 = __ballot(p[(g * 4 + 1) * 64 + lane] != 0.f);
                u64 b2 = __ballot(p[(g * 4 + 2) * 64 + lane] != 0.f);
                u64 b3 = __ballot(p[(g * 4 + 3) * 64 + lane] != 0.f);
                u64 v = (lane == 0) ? b0 : (lane == 1) ? b1 : (lane == 2) ? b2 : b3;
                if (lane < 4) Mlds[row * MST + g * 4 + lane] = v;
            }
        }
    }

    __syncthreads();                       // the ONLY barrier

    const int mrow = lane & 15, kq = (lane >> 4) * 8;
    const int mloc = 16 * wave + mrow;     // block-local row this thread owns
    const float srow = src[i0 + mloc];
    const float mbound = lrelu(srow + MBIAS);   // upper bound of row max

    // B global pointers: row f = 16*nt + mrow, this lane's 8-col chunk
    const u16* bbase = WhT + c0 + kq;
    const size_t brow0 = (size_t)(mrow)      * N_NODES;
    const size_t brow1 = (size_t)(16 + mrow) * N_NODES;
    const size_t brow2 = (size_t)(32 + mrow) * N_NODES;
    const size_t brow3 = (size_t)(48 + mrow) * N_NODES;

    f32x4 acc[4] = {{0,0,0,0},{0,0,0,0},{0,0,0,0},{0,0,0,0}};
    float lacc = 0.f;

    // 1-step B prefetch pipeline over 32 steps (t,ks)
    uint4 bc0 = *(const uint4*)(bbase + brow0);
    uint4 bc1 = *(const uint4*)(bbase + brow1);
    uint4 bc2 = *(const uint4*)(bbase + brow2);
    uint4 bc3 = *(const uint4*)(bbase + brow3);

    for (int s = 0; s < 2 * NTILES; ++s) {
        const int t = s >> 1, ks = s & 1;

        uint4 bn0, bn1, bn2, bn3;
        if (s + 1 < 2 * NTILES) {
            const int off = ((s + 1) >> 1) * 64 + ((s + 1) & 1) * 32;
            bn0 = *(const uint4*)(bbase + brow0 + off);
            bn1 = *(const uint4*)(bbase + brow1 + off);
            bn2 = *(const uint4*)(bbase + brow2 + off);
            bn3 = *(const uint4*)(bbase + brow3 + off);
        }

        // P fragment in-register from LDS mask + dst
        const u64 mword = Mlds[mloc * MST + t];
        const u32 bits = (u32)(mword >> (ks * 32 + kq)) & 0xFFu;
        const float* dp = &Dlds[t * 64 + ks * 32 + kq];
        float4 dd0 = *(const float4*)dp;
        float4 dd1 = *(const float4*)(dp + 4);
        float dv[8] = {dd0.x,dd0.y,dd0.z,dd0.w, dd1.x,dd1.y,dd1.z,dd1.w};
        union { u32 w[4]; bf16x8 v; } pa;
#pragma unroll
        for (int e = 0; e < 4; ++e) {
            float s0 = lrelu(srow + dv[2 * e]);
            float s1 = lrelu(srow + dv[2 * e + 1]);
            float p0 = (bits & (1u << (2 * e)))     ? __expf(s0 - mbound) : 0.f;
            float p1 = (bits & (1u << (2 * e + 1))) ? __expf(s1 - mbound) : 0.f;
            u32 q0 = f2bfbits(p0), q1 = f2bfbits(p1);
            lacc += bf2f(q0) + bf2f(q1);       // l from ROUNDED P
            pa.w[e] = q0 | (q1 << 16);
        }

        acc[0] = __builtin_amdgcn_mfma_f32_16x16x32_bf16(pa.v, *(bf16x8*)&bc0, acc[0], 0, 0, 0);
        acc[1] = __builtin_amdgcn_mfma_f32_16x16x32_bf16(pa.v, *(bf16x8*)&bc1, acc[1], 0, 0, 0);
        acc[2] = __builtin_amdgcn_mfma_f32_16x16x32_bf16(pa.v, *(bf16x8*)&bc2, acc[2], 0, 0, 0);
        acc[3] = __builtin_amdgcn_mfma_f32_16x16x32_bf16(pa.v, *(bf16x8*)&bc3, acc[3], 0, 0, 0);

        bc0 = bn0; bc1 = bn1; bc2 = bn2; bc3 = bn3;
    }

    // l: lanes {mrow, mrow+16, mrow+32, mrow+48} hold row mloc's partials
    lacc += __shfl_xor(lacc, 16, 64);
    lacc += __shfl_xor(lacc, 32, 64);
    if (lane < 16) l_part[blockIdx.y * N_NODES + i0 + 16 * wave + lane] = lacc;

    // C/D layout: col = lane&15, row = (lane>>4)*4 + reg   [m89/m91 verified]
    float* Ob = O_part + (size_t)blockIdx.y * N_NODES * OUT_F;
#pragma unroll
    for (int nt = 0; nt < 4; ++nt)
#pragma unroll
        for (int reg = 0; reg < 4; ++reg) {
            int row = i0 + 16 * wave + (lane >> 4) * 4 + reg;
            int col = 16 * nt + (lane & 15);
            Ob[(size_t)row * OUT_F + col] = acc[nt][reg];
        }
}

// ---------------------------------------------------------------------------
// Kernel 3: out = elu( (sum_c O_c) / (sum_c l_c) ), store per dtype.
// ---------------------------------------------------------------------------
__global__ __launch_bounds__(256) void gat_reduce_kernel(
    const float* __restrict__ O_part, const float* __restrict__ l_part,
    const void* __restrict__ adj, void* __restrict__ out)
{
    int gid = blockIdx.x * 256 + threadIdx.x;
    int i = gid >> 6;
    float O = 0.f, L = 0.f;
#pragma unroll
    for (int c = 0; c < CSPL; ++c) {
        O += O_part[(size_t)c * N_NODES * OUT_F + gid];
        L += l_part[c * N_NODES + i];
    }
    float hp = O / L;
    float o = hp > 0.f ? hp : expm1f(hp);     // elu alpha=1
    if (detect_bf16(adj)) ((u16*)out)[gid] = (u16)f2bfbits(o);
    else                  ((float*)out)[gid] = o;
}

// ---------------------------------------------------------------------------
extern "C" void kernel_launch(void* const* d_in, const int* in_sizes, int n_in,
                              void* d_out, int out_size, void* d_ws, size_t ws_size,
                              hipStream_t stream)
{
    const void* h   = d_in[0];
    const void* adj = d_in[1];
    const void* W   = d_in[2];
    const void* a   = d_in[3];

    char* ws = (char*)d_ws;
    u16*   WhT    = (u16*)ws;                                   // 1 MB
    float* src    = (float*)(ws + (1u << 20));                  // 32 KB
    float* dst    = (float*)(ws + (1u << 20) + 32768);          // 32 KB
    float* O_part = (float*)(ws + (2u << 20));                  // 16 MB (8 splits)
    float* l_part = (float*)(ws + (18u << 20));                 // 256 KB

    gat_wh_kernel<<<N_NODES / 16, 256, 0, stream>>>(h, W, a, adj, WhT, src, dst);
    dim3 grid(N_NODES / 64, CSPL);
    gat_attn_kernel<<<grid, 256, 0, stream>>>(adj, WhT, src, dst, O_part, l_part);
    gat_reduce_kernel<<<N_NODES * OUT_F / 256, 256, 0, stream>>>(O_part, l_part, adj, d_out);
}

// Round 14
// 424.366 us; speedup vs baseline: 1.0804x; 1.0804x over previous
//
#include <hip/hip_runtime.h>
#include <hip/hip_bf16.h>

#define N_NODES 8192
#define IN_F    256
#define OUT_F   64
#define ALPHA   0.3f
#define MBIAS   20.0f            // >= max dst_j; softmax exact after l-division
#define CSPL    8                // column splits
#define COLS_PER (N_NODES / CSPL)    // 1024
#define NTILES  (COLS_PER / 64)      // 16
#define MST     17               // mask LDS row stride (u64): 16 + 1
#define LDP     72               // repack LDS row stride (u16): 64 + 8
#define WH_BLOCKS (N_NODES / 16)     // 512

typedef unsigned short u16;
typedef unsigned int   u32;
typedef unsigned long long u64;
typedef __attribute__((ext_vector_type(8))) short bf16x8;
typedef __attribute__((ext_vector_type(4))) float f32x4;

__device__ __forceinline__ float bf2f(u32 u) { return __uint_as_float(u << 16); }
__device__ __forceinline__ u32 f2bfbits(float x) {          // RNE f32->bf16
    u32 u = __float_as_uint(x);
    return (u + 0x7FFFu + ((u >> 16) & 1u)) >> 16;
}
__device__ __forceinline__ float lrelu(float s) { return s > 0.f ? s : ALPHA * s; }

// dtype probe: adj[0,0] == 1.0 always. bf16 -> low16 of first word = 0x3F80.
__device__ __forceinline__ int detect_bf16(const void* adj) {
    return ((((const u32*)adj)[0] & 0xFFFFu) == 0x3F80u) ? 1 : 0;
}

template <bool BF16>
__device__ __forceinline__ float ld(const void* p, size_t idx) {
    if constexpr (BF16) return bf2f(((const u16*)p)[idx]);
    else                return ((const float*)p)[idx];
}

// ---------------------------------------------------------------------------
// Kernel 1 (fused prep): blocks [0,512): Wh = h @ W  (R9-proven body) ->
// WhT feat-major + src/dst. Blocks [512,2560): adj -> bitmask stream
// (R9-proven lane-strided ballot body, own registers, BW-bound).
// ---------------------------------------------------------------------------
template <bool BF16>
__device__ __forceinline__ void wh4_impl(
    const void* __restrict__ h, const void* __restrict__ W,
    const void* __restrict__ a, float* __restrict__ src,
    float* __restrict__ dst, int i0, int lane, float* accv)
{
    float acc0 = 0.f, acc1 = 0.f, acc2 = 0.f, acc3 = 0.f;
#pragma unroll 8
    for (int k = 0; k < IN_F; ++k) {
        float wv = ld<BF16>(W, (size_t)k * OUT_F + lane);      // coalesced
        float h0 = ld<BF16>(h, (size_t)(i0 + 0) * IN_F + k);   // wave-uniform
        float h1 = ld<BF16>(h, (size_t)(i0 + 1) * IN_F + k);
        float h2 = ld<BF16>(h, (size_t)(i0 + 2) * IN_F + k);
        float h3 = ld<BF16>(h, (size_t)(i0 + 3) * IN_F + k);
        acc0 = fmaf(h0, wv, acc0);
        acc1 = fmaf(h1, wv, acc1);
        acc2 = fmaf(h2, wv, acc2);
        acc3 = fmaf(h3, wv, acc3);
    }
    float av = ld<BF16>(a, lane);
    float bv = ld<BF16>(a, OUT_F + lane);
    float accs[4] = {acc0, acc1, acc2, acc3};
#pragma unroll
    for (int r = 0; r < 4; ++r) {
        float ps = accs[r] * av, pd = accs[r] * bv;
#pragma unroll
        for (int off = 32; off > 0; off >>= 1) {
            ps += __shfl_xor(ps, off, 64);
            pd += __shfl_xor(pd, off, 64);
        }
        if (lane == 0) { src[i0 + r] = ps; dst[i0 + r] = pd; }
        accv[r] = accs[r];
    }
}

__global__ __launch_bounds__(256) void gat_prep_kernel(
    const void* __restrict__ h, const void* __restrict__ W,
    const void* __restrict__ a, const void* __restrict__ adj,
    u16* __restrict__ WhT, float* __restrict__ src, float* __restrict__ dst,
    u64* __restrict__ mask64)
{
    __shared__ float accs[16][OUT_F];
    const int tid = threadIdx.x, wave = tid >> 6, lane = tid & 63;
    const int isbf = detect_bf16(adj);

    if (blockIdx.x < WH_BLOCKS) {
        const int i0 = blockIdx.x * 16 + wave * 4;
        float av[4];
        if (isbf) wh4_impl<true >(h, W, a, src, dst, i0, lane, av);
        else      wh4_impl<false>(h, W, a, src, dst, i0, lane, av);
#pragma unroll
        for (int r = 0; r < 4; ++r) accs[wave * 4 + r][lane] = av[r];
        __syncthreads();
        if (tid < OUT_F) {                // WhT[f][i0..i0+15], bf16 scratch
            u32 w[8];
#pragma unroll
            for (int e = 0; e < 8; ++e) {
                u32 lo = f2bfbits(accs[2 * e][tid]);
                u32 hi = f2bfbits(accs[2 * e + 1][tid]);
                w[e] = lo | (hi << 16);
            }
            u16* dstp = WhT + (size_t)tid * N_NODES + blockIdx.x * 16;
            *(uint4*)dstp       = *(uint4*)&w[0];
            *(uint4*)(dstp + 8) = *(uint4*)&w[4];
        }
    } else {
        const int wgid = (blockIdx.x - WH_BLOCKS) * 4 + wave;
        const int NW   = 2048 * 4;
        const int C    = (N_NODES / 256) * N_NODES;   // 262144 chunks of 256
        if (isbf) {
            const u16* base = (const u16*)adj;
            for (int c = wgid; c < C; c += NW) {
                const u16* p = base + (size_t)c * 256;
                u64 b0 = __ballot(p[lane]       != 0);
                u64 b1 = __ballot(p[64  + lane] != 0);
                u64 b2 = __ballot(p[128 + lane] != 0);
                u64 b3 = __ballot(p[192 + lane] != 0);
                u64 v = (lane == 0) ? b0 : (lane == 1) ? b1 : (lane == 2) ? b2 : b3;
                if (lane < 4) mask64[(size_t)c * 4 + lane] = v;
            }
        } else {
            const float* base = (const float*)adj;
            for (int c = wgid; c < C; c += NW) {
                const float* p = base + (size_t)c * 256;
                u64 b0 = __ballot(p[lane]       != 0.f);
                u64 b1 = __ballot(p[64  + lane] != 0.f);
                u64 b2 = __ballot(p[128 + lane] != 0.f);
                u64 b3 = __ballot(p[192 + lane] != 0.f);
                u64 v = (lane == 0) ? b0 : (lane == 1) ? b1 : (lane == 2) ? b2 : b3;
                if (lane < 4) mask64[(size_t)c * 4 + lane] = v;
            }
        }
    }
}

// ---------------------------------------------------------------------------
// Kernel 2: repack WhT -> WhB fragment-blocked layout.
// WhB[T][nt][ks] = 1 KB fragment: lane l's 16 B at offset l*16 holds
// B[n=l&15][k=(l>>4)*8+j] for tile T (nodes T*64..+63), feats nt*16..+15.
// Makes attn's B-loads ONE contiguous 1 KB segment per instruction.
// Block T: stage 64x64 WhT tile to LDS (row-major, pad 72), then wave nt
// emits 2 fragments via ds_read_b128 + coalesced global_store_dwordx4.
// ---------------------------------------------------------------------------
__global__ __launch_bounds__(256) void gat_repack_kernel(
    const u16* __restrict__ WhT, u16* __restrict__ WhB)
{
    __shared__ alignas(16) u16 Btile[64 * LDP];
    const int tid = threadIdx.x, wave = tid >> 6, lane = tid & 63;
    const int T = blockIdx.x;

    {   // stage: thread (f=tid>>2, q=tid&3) copies 16 cols (32 B)
        const int f = tid >> 2, q = tid & 3;
        const u16* g = WhT + (size_t)f * N_NODES + T * 64 + q * 16;
        *(uint4*)&Btile[f * LDP + q * 16]     = *(const uint4*)g;
        *(uint4*)&Btile[f * LDP + q * 16 + 8] = *(const uint4*)(g + 8);
    }
    __syncthreads();

    const int nt = wave, mrow = lane & 15, kq = (lane >> 4) * 8;
#pragma unroll
    for (int ks = 0; ks < 2; ++ks) {
        uint4 frag = *(uint4*)&Btile[(16 * nt + mrow) * LDP + ks * 32 + kq];
        u16* out = WhB + ((size_t)T * 8 + nt * 2 + ks) * 512 + lane * 8;
        *(uint4*)out = frag;            // 64 lanes x 16 B = contiguous 1 KB
    }
}

// ---------------------------------------------------------------------------
// Kernel 3: masked-softmax @ Wh via MFMA. Block = 64 rows x 1024 cols,
// grid 128x8. Prologue: mask window (8.5 KB) + dst window (4 KB) to LDS,
// ONE barrier. K-loop (32 steps): barrier-free; P in-register (A-layout,
// R12-proven); B = 4 perfectly-coalesced 1 KB loads from WhB w/ 1-step
// prefetch. No HBM in the loop (WhB 1 MB, L2/L3-resident).
// ---------------------------------------------------------------------------
__global__ __launch_bounds__(256, 4) void gat_attn_kernel(
    const u64* __restrict__ mask64, const u16* __restrict__ WhB,
    const float* __restrict__ src, const float* __restrict__ dst,
    float* __restrict__ O_part, float* __restrict__ l_part)
{
    __shared__ alignas(16) u64  Mlds[64 * MST];     // 8704 B
    __shared__ alignas(16) float Dlds[COLS_PER];    // 4096 B

    const int tid = threadIdx.x, wave = tid >> 6, lane = tid & 63;
    const int i0 = blockIdx.x * 64, c0 = blockIdx.y * COLS_PER;

    // stage mask window: row=tid>>2 (16 u64), thread covers 4 u64 (32 B)
    {
        const int r = tid >> 2, q = tid & 3;
        const u64* g = mask64 + (size_t)(i0 + r) * (N_NODES / 64) + (c0 >> 6) + q * 4;
        *(uint4*)&Mlds[r * MST + q * 4]     = *(const uint4*)g;
        *(uint4*)&Mlds[r * MST + q * 4 + 2] = *(const uint4*)(g + 2);
    }
    // stage dst window (coalesced)
#pragma unroll
    for (int q = 0; q < COLS_PER / 256; ++q)
        Dlds[q * 256 + tid] = dst[c0 + q * 256 + tid];

    __syncthreads();                       // the ONLY barrier

    const int mrow = lane & 15, kq = (lane >> 4) * 8;
    const int mloc = 16 * wave + mrow;     // block-local row this thread owns
    const float srow = src[i0 + mloc];
    const float mbound = lrelu(srow + MBIAS);   // upper bound of row max

    // fragment base: WhB + T*4096 + (nt*2+ks)*512 + lane*8  (u16 units)
    const u16* fb = WhB + (size_t)(blockIdx.y * NTILES) * 4096 + lane * 8;

    f32x4 acc[4] = {{0,0,0,0},{0,0,0,0},{0,0,0,0},{0,0,0,0}};
    float lacc = 0.f;

    // 1-step prefetch over 32 steps s = (t, ks)
    uint4 bc0 = *(const uint4*)(fb);             // t0 ks0: nt 0..3
    uint4 bc1 = *(const uint4*)(fb + 1024);
    uint4 bc2 = *(const uint4*)(fb + 2048);
    uint4 bc3 = *(const uint4*)(fb + 3072);

    for (int s = 0; s < 2 * NTILES; ++s) {
        const int t = s >> 1, ks = s & 1;

        uint4 bn0, bn1, bn2, bn3;
        if (s + 1 < 2 * NTILES) {
            const int off = ((s + 1) >> 1) * 4096 + ((s + 1) & 1) * 512;
            bn0 = *(const uint4*)(fb + off);
            bn1 = *(const uint4*)(fb + off + 1024);
            bn2 = *(const uint4*)(fb + off + 2048);
            bn3 = *(const uint4*)(fb + off + 3072);
        }

        // P fragment in-register from LDS mask + dst
        const u64 mword = Mlds[mloc * MST + t];
        const u32 bits = (u32)(mword >> (ks * 32 + kq)) & 0xFFu;
        const float* dp = &Dlds[t * 64 + ks * 32 + kq];
        float4 dd0 = *(const float4*)dp;         // broadcast b128 reads
        float4 dd1 = *(const float4*)(dp + 4);
        float dv[8] = {dd0.x,dd0.y,dd0.z,dd0.w, dd1.x,dd1.y,dd1.z,dd1.w};
        union { u32 w[4]; bf16x8 v; } pa;
#pragma unroll
        for (int e = 0; e < 4; ++e) {
            float s0 = lrelu(srow + dv[2 * e]);
            float s1 = lrelu(srow + dv[2 * e + 1]);
            float p0 = (bits & (1u << (2 * e)))     ? __expf(s0 - mbound) : 0.f;
            float p1 = (bits & (1u << (2 * e + 1))) ? __expf(s1 - mbound) : 0.f;
            u32 q0 = f2bfbits(p0), q1 = f2bfbits(p1);
            lacc += bf2f(q0) + bf2f(q1);         // l from ROUNDED P
            pa.w[e] = q0 | (q1 << 16);
        }

        acc[0] = __builtin_amdgcn_mfma_f32_16x16x32_bf16(pa.v, *(bf16x8*)&bc0, acc[0], 0, 0, 0);
        acc[1] = __builtin_amdgcn_mfma_f32_16x16x32_bf16(pa.v, *(bf16x8*)&bc1, acc[1], 0, 0, 0);
        acc[2] = __builtin_amdgcn_mfma_f32_16x16x32_bf16(pa.v, *(bf16x8*)&bc2, acc[2], 0, 0, 0);
        acc[3] = __builtin_amdgcn_mfma_f32_16x16x32_bf16(pa.v, *(bf16x8*)&bc3, acc[3], 0, 0, 0);

        bc0 = bn0; bc1 = bn1; bc2 = bn2; bc3 = bn3;
    }

    // l: lanes {mrow, mrow+16, mrow+32, mrow+48} hold row mloc's partials
    lacc += __shfl_xor(lacc, 16, 64);
    lacc += __shfl_xor(lacc, 32, 64);
    if (lane < 16) l_part[blockIdx.y * N_NODES + i0 + 16 * wave + lane] = lacc;

    // C/D layout: col = lane&15, row = (lane>>4)*4 + reg   [m89/m91 verified]
    float* Ob = O_part + (size_t)blockIdx.y * N_NODES * OUT_F;
#pragma unroll
    for (int nt = 0; nt < 4; ++nt)
#pragma unroll
        for (int reg = 0; reg < 4; ++reg) {
            int row = i0 + 16 * wave + (lane >> 4) * 4 + reg;
            int col = 16 * nt + (lane & 15);
            Ob[(size_t)row * OUT_F + col] = acc[nt][reg];
        }
}

// ---------------------------------------------------------------------------
// Kernel 4: out = elu( (sum_c O_c) / (sum_c l_c) ), store per dtype.
// ---------------------------------------------------------------------------
__global__ __launch_bounds__(256) void gat_reduce_kernel(
    const float* __restrict__ O_part, const float* __restrict__ l_part,
    const void* __restrict__ adj, void* __restrict__ out)
{
    int gid = blockIdx.x * 256 + threadIdx.x;
    int i = gid >> 6;
    float O = 0.f, L = 0.f;
#pragma unroll
    for (int c = 0; c < CSPL; ++c) {
        O += O_part[(size_t)c * N_NODES * OUT_F + gid];
        L += l_part[c * N_NODES + i];
    }
    float hp = O / L;
    float o = hp > 0.f ? hp : expm1f(hp);     // elu alpha=1
    if (detect_bf16(adj)) ((u16*)out)[gid] = (u16)f2bfbits(o);
    else                  ((float*)out)[gid] = o;
}

// ---------------------------------------------------------------------------
extern "C" void kernel_launch(void* const* d_in, const int* in_sizes, int n_in,
                              void* d_out, int out_size, void* d_ws, size_t ws_size,
                              hipStream_t stream)
{
    const void* h   = d_in[0];
    const void* adj = d_in[1];
    const void* W   = d_in[2];
    const void* a   = d_in[3];

    char* ws = (char*)d_ws;
    u16*   WhT    = (u16*)ws;                                   // 1 MB
    u16*   WhB    = (u16*)(ws + (1u << 20));                    // 1 MB
    float* src    = (float*)(ws + (2u << 20));                  // 32 KB
    float* dst    = (float*)(ws + (2u << 20) + 32768);          // 32 KB
    u64*   mask64 = (u64*)  (ws + (3u << 20));                  // 8 MB
    float* O_part = (float*)(ws + (16u << 20));                 // 16 MB (8 splits)
    float* l_part = (float*)(ws + (32u << 20));                 // 256 KB

    gat_prep_kernel<<<WH_BLOCKS + 2048, 256, 0, stream>>>(h, W, a, adj, WhT, src, dst, mask64);
    gat_repack_kernel<<<N_NODES / 64, 256, 0, stream>>>(WhT, WhB);
    dim3 grid(N_NODES / 64, CSPL);
    gat_attn_kernel<<<grid, 256, 0, stream>>>(mask64, WhB, src, dst, O_part, l_part);
    gat_reduce_kernel<<<N_NODES * OUT_F / 256, 256, 0, stream>>>(O_part, l_part, adj, d_out);
}

// Round 15
// 421.020 us; speedup vs baseline: 1.0890x; 1.0079x over previous
//
#include <hip/hip_runtime.h>
#include <hip/hip_bf16.h>

#define N_NODES 8192
#define IN_F    256
#define OUT_F   64
#define ALPHA   0.3f
#define MBIAS   20.0f            // >= max dst_j; softmax exact after l-division
#define CSPL    8                // column splits
#define COLS_PER (N_NODES / CSPL)    // 1024
#define NTILES  (COLS_PER / 64)      // 16
#define MST     17               // mask LDS row stride (u64): 16 + 1
#define WH_BLOCKS (N_NODES / 16)     // 512

typedef unsigned short u16;
typedef unsigned int   u32;
typedef unsigned long long u64;
typedef __attribute__((ext_vector_type(8))) short bf16x8;
typedef __attribute__((ext_vector_type(4))) float f32x4;

__device__ __forceinline__ float bf2f(u32 u) { return __uint_as_float(u << 16); }
__device__ __forceinline__ u32 f2bfbits(float x) {          // RNE f32->bf16
    u32 u = __float_as_uint(x);
    return (u + 0x7FFFu + ((u >> 16) & 1u)) >> 16;
}
__device__ __forceinline__ float lrelu(float s) { return s > 0.f ? s : ALPHA * s; }

// dtype probe: adj[0,0] == 1.0 always. bf16 -> low16 of first word = 0x3F80.
__device__ __forceinline__ int detect_bf16(const void* adj) {
    return ((((const u32*)adj)[0] & 0xFFFFu) == 0x3F80u) ? 1 : 0;
}

template <bool BF16>
__device__ __forceinline__ float ld(const void* p, size_t idx) {
    if constexpr (BF16) return bf2f(((const u16*)p)[idx]);
    else                return ((const float*)p)[idx];
}

// ---------------------------------------------------------------------------
// Kernel 1 (fused prep):
// blocks [0,512): Wh = h @ W (R9-proven math) -> WhB written DIRECTLY in
//   fragment-blocked layout (no WhT, no repack kernel) + src/dst fp32.
//   Block b covers nodes b*16..b*16+15 = quarter q=b&3 of tile T=b>>2;
//   fragment (T,nt,ks=q>>1) gets its k-positions q*16..q*16+15 from lanes
//   with (kg>>1)==(q&1):  ks*32+kg*8 == q*16+(kg&1)*8  (verified bijection).
// blocks [512,2560): adj -> bitmask stream (R9-proven ballot body).
// ---------------------------------------------------------------------------
template <bool BF16>
__device__ __forceinline__ void wh4_impl(
    const void* __restrict__ h, const void* __restrict__ W,
    const void* __restrict__ a, float* __restrict__ src,
    float* __restrict__ dst, int i0, int lane, float* accv)
{
    float acc0 = 0.f, acc1 = 0.f, acc2 = 0.f, acc3 = 0.f;
#pragma unroll 8
    for (int k = 0; k < IN_F; ++k) {
        float wv = ld<BF16>(W, (size_t)k * OUT_F + lane);      // coalesced
        float h0 = ld<BF16>(h, (size_t)(i0 + 0) * IN_F + k);   // wave-uniform
        float h1 = ld<BF16>(h, (size_t)(i0 + 1) * IN_F + k);
        float h2 = ld<BF16>(h, (size_t)(i0 + 2) * IN_F + k);
        float h3 = ld<BF16>(h, (size_t)(i0 + 3) * IN_F + k);
        acc0 = fmaf(h0, wv, acc0);
        acc1 = fmaf(h1, wv, acc1);
        acc2 = fmaf(h2, wv, acc2);
        acc3 = fmaf(h3, wv, acc3);
    }
    float av = ld<BF16>(a, lane);
    float bv = ld<BF16>(a, OUT_F + lane);
    float accs[4] = {acc0, acc1, acc2, acc3};
#pragma unroll
    for (int r = 0; r < 4; ++r) {
        float ps = accs[r] * av, pd = accs[r] * bv;
#pragma unroll
        for (int off = 32; off > 0; off >>= 1) {
            ps += __shfl_xor(ps, off, 64);
            pd += __shfl_xor(pd, off, 64);
        }
        if (lane == 0) { src[i0 + r] = ps; dst[i0 + r] = pd; }
        accv[r] = accs[r];
    }
}

__global__ __launch_bounds__(256) void gat_prep_kernel(
    const void* __restrict__ h, const void* __restrict__ W,
    const void* __restrict__ a, const void* __restrict__ adj,
    u16* __restrict__ WhB, float* __restrict__ src, float* __restrict__ dst,
    u64* __restrict__ mask64)
{
    __shared__ float accs[16][OUT_F];
    const int tid = threadIdx.x, wave = tid >> 6, lane = tid & 63;
    const int isbf = detect_bf16(adj);

    if (blockIdx.x < WH_BLOCKS) {
        const int i0 = blockIdx.x * 16 + wave * 4;
        float av[4];
        if (isbf) wh4_impl<true >(h, W, a, src, dst, i0, lane, av);
        else      wh4_impl<false>(h, W, a, src, dst, i0, lane, av);
#pragma unroll
        for (int r = 0; r < 4; ++r) accs[wave * 4 + r][lane] = av[r];
        __syncthreads();

        // direct fragment-blocked WhB write (replaces WhT + repack kernel)
        const int T = blockIdx.x >> 2, q = blockIdx.x & 3;
        const int nt = wave, n = lane & 15, kg = lane >> 4;
        if ((kg >> 1) == (q & 1)) {
            const int ln0 = (kg & 1) * 8;        // local node base for j=0..7
            u32 w[4];
#pragma unroll
            for (int e = 0; e < 4; ++e) {
                u32 lo = f2bfbits(accs[ln0 + 2 * e][nt * 16 + n]);
                u32 hi = f2bfbits(accs[ln0 + 2 * e + 1][nt * 16 + n]);
                w[e] = lo | (hi << 16);
            }
            u16* out = WhB + ((size_t)T * 8 + nt * 2 + (q >> 1)) * 512 + lane * 8;
            *(uint4*)out = *(uint4*)w;
        }
    } else {
        const int wgid = (blockIdx.x - WH_BLOCKS) * 4 + wave;
        const int NW   = 2048 * 4;
        const int C    = (N_NODES / 256) * N_NODES;   // 262144 chunks of 256
        if (isbf) {
            const u16* base = (const u16*)adj;
            for (int c = wgid; c < C; c += NW) {
                const u16* p = base + (size_t)c * 256;
                u64 b0 = __ballot(p[lane]       != 0);
                u64 b1 = __ballot(p[64  + lane] != 0);
                u64 b2 = __ballot(p[128 + lane] != 0);
                u64 b3 = __ballot(p[192 + lane] != 0);
                u64 v = (lane == 0) ? b0 : (lane == 1) ? b1 : (lane == 2) ? b2 : b3;
                if (lane < 4) mask64[(size_t)c * 4 + lane] = v;
            }
        } else {
            const float* base = (const float*)adj;
            for (int c = wgid; c < C; c += NW) {
                const float* p = base + (size_t)c * 256;
                u64 b0 = __ballot(p[lane]       != 0.f);
                u64 b1 = __ballot(p[64  + lane] != 0.f);
                u64 b2 = __ballot(p[128 + lane] != 0.f);
                u64 b3 = __ballot(p[192 + lane] != 0.f);
                u64 v = (lane == 0) ? b0 : (lane == 1) ? b1 : (lane == 2) ? b2 : b3;
                if (lane < 4) mask64[(size_t)c * 4 + lane] = v;
            }
        }
    }
}

// ---------------------------------------------------------------------------
// Kernel 2: masked-softmax @ Wh via MFMA (R14-proven, verbatim).
// Block = 64 rows x 1024 cols, grid 128x8. Prologue: mask window (8.5 KB) +
// dst window (4 KB) to LDS, ONE barrier. K-loop (32 steps): barrier-free;
// P in-register (A-layout); B = 4 perfectly-coalesced 1 KB loads from WhB
// with 1-step prefetch. No HBM in the loop (WhB 1 MB, L2/L3-resident).
// ---------------------------------------------------------------------------
__global__ __launch_bounds__(256, 4) void gat_attn_kernel(
    const u64* __restrict__ mask64, const u16* __restrict__ WhB,
    const float* __restrict__ src, const float* __restrict__ dst,
    float* __restrict__ O_part, float* __restrict__ l_part)
{
    __shared__ alignas(16) u64  Mlds[64 * MST];     // 8704 B
    __shared__ alignas(16) float Dlds[COLS_PER];    // 4096 B

    const int tid = threadIdx.x, wave = tid >> 6, lane = tid & 63;
    const int i0 = blockIdx.x * 64, c0 = blockIdx.y * COLS_PER;

    // stage mask window: row=tid>>2 (16 u64), thread covers 4 u64 (32 B)
    {
        const int r = tid >> 2, q = tid & 3;
        const u64* g = mask64 + (size_t)(i0 + r) * (N_NODES / 64) + (c0 >> 6) + q * 4;
        *(uint4*)&Mlds[r * MST + q * 4]     = *(const uint4*)g;
        *(uint4*)&Mlds[r * MST + q * 4 + 2] = *(const uint4*)(g + 2);
    }
    // stage dst window (coalesced)
#pragma unroll
    for (int q = 0; q < COLS_PER / 256; ++q)
        Dlds[q * 256 + tid] = dst[c0 + q * 256 + tid];

    __syncthreads();                       // the ONLY barrier

    const int mrow = lane & 15, kq = (lane >> 4) * 8;
    const int mloc = 16 * wave + mrow;     // block-local row this thread owns
    const float srow = src[i0 + mloc];
    const float mbound = lrelu(srow + MBIAS);   // upper bound of row max

    // fragment base: WhB + T*4096 + (nt*2+ks)*512 + lane*8  (u16 units)
    const u16* fb = WhB + (size_t)(blockIdx.y * NTILES) * 4096 + lane * 8;

    f32x4 acc[4] = {{0,0,0,0},{0,0,0,0},{0,0,0,0},{0,0,0,0}};
    float lacc = 0.f;

    // 1-step prefetch over 32 steps s = (t, ks)
    uint4 bc0 = *(const uint4*)(fb);             // t0 ks0: nt 0..3
    uint4 bc1 = *(const uint4*)(fb + 1024);
    uint4 bc2 = *(const uint4*)(fb + 2048);
    uint4 bc3 = *(const uint4*)(fb + 3072);

    for (int s = 0; s < 2 * NTILES; ++s) {
        const int t = s >> 1, ks = s & 1;

        uint4 bn0, bn1, bn2, bn3;
        if (s + 1 < 2 * NTILES) {
            const int off = ((s + 1) >> 1) * 4096 + ((s + 1) & 1) * 512;
            bn0 = *(const uint4*)(fb + off);
            bn1 = *(const uint4*)(fb + off + 1024);
            bn2 = *(const uint4*)(fb + off + 2048);
            bn3 = *(const uint4*)(fb + off + 3072);
        }

        // P fragment in-register from LDS mask + dst
        const u64 mword = Mlds[mloc * MST + t];
        const u32 bits = (u32)(mword >> (ks * 32 + kq)) & 0xFFu;
        const float* dp = &Dlds[t * 64 + ks * 32 + kq];
        float4 dd0 = *(const float4*)dp;         // broadcast b128 reads
        float4 dd1 = *(const float4*)(dp + 4);
        float dv[8] = {dd0.x,dd0.y,dd0.z,dd0.w, dd1.x,dd1.y,dd1.z,dd1.w};
        union { u32 w[4]; bf16x8 v; } pa;
#pragma unroll
        for (int e = 0; e < 4; ++e) {
            float s0 = lrelu(srow + dv[2 * e]);
            float s1 = lrelu(srow + dv[2 * e + 1]);
            float p0 = (bits & (1u << (2 * e)))     ? __expf(s0 - mbound) : 0.f;
            float p1 = (bits & (1u << (2 * e + 1))) ? __expf(s1 - mbound) : 0.f;
            u32 q0 = f2bfbits(p0), q1 = f2bfbits(p1);
            lacc += bf2f(q0) + bf2f(q1);         // l from ROUNDED P
            pa.w[e] = q0 | (q1 << 16);
        }

        acc[0] = __builtin_amdgcn_mfma_f32_16x16x32_bf16(pa.v, *(bf16x8*)&bc0, acc[0], 0, 0, 0);
        acc[1] = __builtin_amdgcn_mfma_f32_16x16x32_bf16(pa.v, *(bf16x8*)&bc1, acc[1], 0, 0, 0);
        acc[2] = __builtin_amdgcn_mfma_f32_16x16x32_bf16(pa.v, *(bf16x8*)&bc2, acc[2], 0, 0, 0);
        acc[3] = __builtin_amdgcn_mfma_f32_16x16x32_bf16(pa.v, *(bf16x8*)&bc3, acc[3], 0, 0, 0);

        bc0 = bn0; bc1 = bn1; bc2 = bn2; bc3 = bn3;
    }

    // l: lanes {mrow, mrow+16, mrow+32, mrow+48} hold row mloc's partials
    lacc += __shfl_xor(lacc, 16, 64);
    lacc += __shfl_xor(lacc, 32, 64);
    if (lane < 16) l_part[blockIdx.y * N_NODES + i0 + 16 * wave + lane] = lacc;

    // C/D layout: col = lane&15, row = (lane>>4)*4 + reg   [m89/m91 verified]
    float* Ob = O_part + (size_t)blockIdx.y * N_NODES * OUT_F;
#pragma unroll
    for (int nt = 0; nt < 4; ++nt)
#pragma unroll
        for (int reg = 0; reg < 4; ++reg) {
            int row = i0 + 16 * wave + (lane >> 4) * 4 + reg;
            int col = 16 * nt + (lane & 15);
            Ob[(size_t)row * OUT_F + col] = acc[nt][reg];
        }
}

// ---------------------------------------------------------------------------
// Kernel 3: out = elu( (sum_c O_c) / (sum_c l_c) ), store per dtype.
// ---------------------------------------------------------------------------
__global__ __launch_bounds__(256) void gat_reduce_kernel(
    const float* __restrict__ O_part, const float* __restrict__ l_part,
    const void* __restrict__ adj, void* __restrict__ out)
{
    int gid = blockIdx.x * 256 + threadIdx.x;
    int i = gid >> 6;
    float O = 0.f, L = 0.f;
#pragma unroll
    for (int c = 0; c < CSPL; ++c) {
        O += O_part[(size_t)c * N_NODES * OUT_F + gid];
        L += l_part[c * N_NODES + i];
    }
    float hp = O / L;
    float o = hp > 0.f ? hp : expm1f(hp);     // elu alpha=1
    if (detect_bf16(adj)) ((u16*)out)[gid] = (u16)f2bfbits(o);
    else                  ((float*)out)[gid] = o;
}

// ---------------------------------------------------------------------------
extern "C" void kernel_launch(void* const* d_in, const int* in_sizes, int n_in,
                              void* d_out, int out_size, void* d_ws, size_t ws_size,
                              hipStream_t stream)
{
    const void* h   = d_in[0];
    const void* adj = d_in[1];
    const void* W   = d_in[2];
    const void* a   = d_in[3];

    char* ws = (char*)d_ws;
    u16*   WhB    = (u16*)ws;                                   // 1 MB
    float* src    = (float*)(ws + (1u << 20));                  // 32 KB
    float* dst    = (float*)(ws + (1u << 20) + 32768);          // 32 KB
    u64*   mask64 = (u64*)  (ws + (3u << 20));                  // 8 MB
    float* O_part = (float*)(ws + (16u << 20));                 // 16 MB (8 splits)
    float* l_part = (float*)(ws + (32u << 20));                 // 256 KB

    gat_prep_kernel<<<WH_BLOCKS + 2048, 256, 0, stream>>>(h, W, a, adj, WhB, src, dst, mask64);
    dim3 grid(N_NODES / 64, CSPL);
    gat_attn_kernel<<<grid, 256, 0, stream>>>(mask64, WhB, src, dst, O_part, l_part);
    gat_reduce_kernel<<<N_NODES * OUT_F / 256, 256, 0, stream>>>(O_part, l_part, adj, d_out);
}